// Round 5
// baseline (539.867 us; speedup 1.0000x reference)
//
#include <hip/hip_runtime.h>
#include <hip/hip_bf16.h>
#include <math.h>

#define S_LEN 2048
#define HID   4096
#define NQKV  6144
#define NHEAD 32
#define NKVH  8
#define HDIM  128

typedef __attribute__((ext_vector_type(8))) short short8;
typedef __attribute__((ext_vector_type(4))) short short4v;
typedef __attribute__((ext_vector_type(4))) float f32x4;

__device__ __forceinline__ unsigned short f2bf(float f) {
    union { float f; unsigned u; } v; v.f = f;
    unsigned r = v.u + 0x7fffu + ((v.u >> 16) & 1u);
    return (unsigned short)(r >> 16);
}

// ---------------- fp32 -> bf16 convert ----------------
__global__ __launch_bounds__(256)
void cvt_kernel(const float* __restrict__ in, unsigned short* __restrict__ out, int n) {
    int idx = (blockIdx.x * 256 + threadIdx.x) * 4;
    int stride = gridDim.x * 256 * 4;
    for (; idx < n; idx += stride) {
        float4 v = *(const float4*)(in + idx);
        ushort4 o;
        o.x = f2bf(v.x); o.y = f2bf(v.y); o.z = f2bf(v.z); o.w = f2bf(v.w);
        *(ushort4*)(out + idx) = o;
    }
}

// ---------------- FWHT over 4096, * su, * 1/4096, -> bf16 ----------------
__global__ __launch_bounds__(256)
void fwht_kernel(const float* __restrict__ in, const float* __restrict__ su,
                 unsigned short* __restrict__ out) {
    __shared__ float buf[HID];
    const float* src = in + (size_t)blockIdx.x * HID;
    for (int i = threadIdx.x; i < HID; i += 256) buf[i] = src[i] * su[i];
    __syncthreads();
    int lg = 0;
    for (int h = 1; h < HID; h <<= 1, ++lg) {
        for (int p = threadIdx.x; p < HID / 2; p += 256) {
            int j  = p & (h - 1);
            int i0 = ((p >> lg) << (lg + 1)) | j;
            int i1 = i0 + h;
            float a = buf[i0], b = buf[i1];
            buf[i0] = a + b;
            buf[i1] = a - b;
        }
        __syncthreads();
    }
    unsigned short* dst = out + (size_t)blockIdx.x * HID;
    const float norm = 1.0f / 4096.0f;   // (1/sqrt(4096)) * (1/SCALE)
    for (int i = threadIdx.x; i < HID; i += 256) dst[i] = f2bf(buf[i] * norm);
}

// ---------------- quad-buffered bf16 GEMM, BK=32, XCD-chunked ----------------
// C[m][n] = (sum_k A[m][k]*B[n][k]) * scale[n] * 64
// BM=256 (waves 2Mx4N, per-wave 128x64) or BM=128 (per-wave 64x64). BN=256.
// 4 LDS slots; stage tile t+3 issued at top of tile t -> 2 tiles of slack
// before the counted vmcnt drain. One barrier per tile. Swizzle within the
// 64-byte K-row: byte ^= (row&6)<<3 (2-way bank aliasing on reads = free).
template<int BM>
__global__ __launch_bounds__(512, 1)
void gemm_q(const unsigned short* __restrict__ A, const unsigned short* __restrict__ B,
            const float* __restrict__ scale, float* __restrict__ C,
            int M, int N, int K) {
    constexpr int MW  = BM / 2;          // per-wave M rows
    constexpr int MF  = MW / 16;         // m-frags per wave
    constexpr int LPA = BM / 128;        // A gload_lds per thread per tile (2 or 1)
    constexpr int L   = LPA + 2;         // total loads per thread per tile
    __shared__ __attribute__((aligned(16))) unsigned short As[4][BM * 32];
    __shared__ __attribute__((aligned(16))) unsigned short Bs[4][256 * 32];

    // bijective XCD-chunk remap (nwg % 8 == 0)
    const int nwg = gridDim.x;
    const int id  = blockIdx.x;
    const int wg  = (id & 7) * (nwg >> 3) + (id >> 3);
    const int bmc = M / BM;
    const int bn  = wg / bmc, bm = wg % bmc;

    const int tid = threadIdx.x;
    const int wv = tid >> 6, lane = tid & 63;
    const int wr = wv >> 2, wc = wv & 3;
    const int lr = lane & 15, lgp = lane >> 4;

    f32x4 acc[MF][4] = {};

    const unsigned short* Abase = A + (size_t)(bm * BM) * K;
    const unsigned short* Bbase = B + (size_t)(bn * 256) * K;

    auto stage = [&](int slot, int kt) {
#pragma unroll
        for (int c = 0; c < LPA; ++c) {
            int o = (c * 512 + tid) * 16;                 // linear LDS byte offset
            int row = o >> 6;
            int cb = (o & 63) ^ ((row & 6) << 3);         // inverse-swizzled src byte col
            __builtin_amdgcn_global_load_lds(
                (const __attribute__((address_space(1))) void*)(Abase + (size_t)row * K + kt * 32 + (cb >> 1)),
                (__attribute__((address_space(3))) void*)&As[slot][o >> 1], 16, 0, 0);
        }
#pragma unroll
        for (int c = 0; c < 2; ++c) {
            int o = (c * 512 + tid) * 16;
            int row = o >> 6;
            int cb = (o & 63) ^ ((row & 6) << 3);
            __builtin_amdgcn_global_load_lds(
                (const __attribute__((address_space(1))) void*)(Bbase + (size_t)row * K + kt * 32 + (cb >> 1)),
                (__attribute__((address_space(3))) void*)&Bs[slot][o >> 1], 16, 0, 0);
        }
    };

    const int NT = K >> 5;
    stage(0, 0); stage(1, 1); stage(2, 2);

    for (int t = 0; t < NT; ++t) {
        const int slot = t & 3;
        // drain this tile's loads; keep up to 2 tiles in flight
        if (t < NT - 2) {
            if constexpr (L == 4) asm volatile("s_waitcnt vmcnt(8)" ::: "memory");
            else                  asm volatile("s_waitcnt vmcnt(6)" ::: "memory");
        } else if (t == NT - 2) {
            if constexpr (L == 4) asm volatile("s_waitcnt vmcnt(4)" ::: "memory");
            else                  asm volatile("s_waitcnt vmcnt(3)" ::: "memory");
        } else {
            asm volatile("s_waitcnt vmcnt(0)" ::: "memory");
        }
        __builtin_amdgcn_s_barrier();     // all waves' tile-t writes visible; tile t-1 reads done
        if (t + 3 < NT) stage((t + 3) & 3, t + 3);
        __builtin_amdgcn_sched_barrier(0);  // keep stage issue ahead of ds_reads

        short8 bfr[4];
#pragma unroll
        for (int n2 = 0; n2 < 4; ++n2) {
            int row = wc * 64 + n2 * 16 + lr;
            bfr[n2] = *(const short8*)&Bs[slot][(row * 64 + (lgp * 16 ^ ((row & 6) << 3))) >> 1];
        }
        short8 af[MF];
#pragma unroll
        for (int m = 0; m < MF; ++m) {
            int row = wr * MW + m * 16 + lr;
            af[m] = *(const short8*)&As[slot][(row * 64 + (lgp * 16 ^ ((row & 6) << 3))) >> 1];
        }
        __builtin_amdgcn_s_setprio(1);
#pragma unroll
        for (int m = 0; m < MF; ++m)
#pragma unroll
            for (int n2 = 0; n2 < 4; ++n2)
                acc[m][n2] = __builtin_amdgcn_mfma_f32_16x16x32_bf16(af[m], bfr[n2], acc[m][n2], 0, 0, 0);
        __builtin_amdgcn_s_setprio(0);
    }

#pragma unroll
    for (int n2 = 0; n2 < 4; ++n2) {
        int gn = bn * 256 + wc * 64 + n2 * 16 + lr;
        float sc = scale[gn] * 64.0f;
#pragma unroll
        for (int m2 = 0; m2 < MF; ++m2) {
            int gm0 = bm * BM + wr * MW + m2 * 16 + lgp * 4;
#pragma unroll
            for (int i = 0; i < 4; ++i)
                C[(size_t)(gm0 + i) * N + gn] = acc[m2][n2][i] * sc;
        }
    }
}

// ---------------- RoPE + relayout to head-major bf16 Q/K/V ----------------
// Q is pre-scaled by 1/sqrt(HDIM) so attention skips the softmax scale.
__global__ __launch_bounds__(256)
void rope_kernel(const float* __restrict__ qkv, const int* __restrict__ pos,
                 unsigned short* __restrict__ Qb, unsigned short* __restrict__ Kb,
                 unsigned short* __restrict__ Vb) {
    const int s = blockIdx.x;
    const float p = (float)pos[s];
    const float* row = qkv + (size_t)s * NQKV;
    const float sm = 0.08838834764831845f;   // 1/sqrt(128)
    for (int idx = threadIdx.x; idx < NQKV; idx += 256) {
        float v = row[idx];
        if (idx < HID + NKVH * HDIM) {      // q or k -> RoPE
            int base = (idx < HID) ? 0 : HID;
            int rel = idx - base;
            int h = rel >> 7, d = rel & 127;
            int j = d & 63;
            float invf = expf((float)j * (-13.122363377404329f / 64.0f)); // theta^(-2j/128)
            float ang = p * invf;
            float sn, cs;
            sincosf(ang, &sn, &cs);
            float other = (d < 64) ? -row[base + h * 128 + d + 64]
                                   :  row[base + h * 128 + d - 64];
            float r = v * cs + other * sn;
            if (idx < HID) Qb[((size_t)h * S_LEN + s) * HDIM + d] = f2bf(r * sm);
            else           Kb[((size_t)h * S_LEN + s) * HDIM + d] = f2bf(r);
        } else {                             // v passthrough
            int rel = idx - (HID + NKVH * HDIM);
            int h = rel >> 7, d = rel & 127;
            Vb[((size_t)h * S_LEN + s) * HDIM + d] = f2bf(v);
        }
    }
}

// ---------------- causal GQA flash attention (swapped QK^T, in-reg softmax) ----------------
__global__ __launch_bounds__(256)
void attn_kernel(const unsigned short* __restrict__ Q, const unsigned short* __restrict__ K,
                 const unsigned short* __restrict__ V, float* __restrict__ O) {
    const int qt = 31 - (int)blockIdx.x;
    const int h  = blockIdx.y;
    const int kvh = h >> 2;
    const int tid = threadIdx.x, wv = tid >> 6, lane = tid & 63;
    const int lr = lane & 15, lgp = lane >> 4;

    __shared__ __attribute__((aligned(16))) unsigned short Ks[2][64 * 128];
    __shared__ __attribute__((aligned(16))) unsigned short Vt[128 * 64];

    int koff[4];
#pragma unroll
    for (int j = 0; j < 4; ++j) {
        int a = (wv * 4 + j) * 512 + lane * 8;
        koff[j] = a ^ (((a >> 7) & 7) << 3);
    }
    const unsigned short* Kg = K + (size_t)kvh * S_LEN * HDIM;
    const unsigned short* Vg = V + (size_t)kvh * S_LEN * HDIM;

    auto stageK = [&](int buf, int kb) {
        const unsigned short* kg = Kg + (size_t)kb * 64 * HDIM;
#pragma unroll
        for (int j = 0; j < 4; ++j) {
            __builtin_amdgcn_global_load_lds(
                (const __attribute__((address_space(1))) void*)(kg + koff[j]),
                (__attribute__((address_space(3))) void*)&Ks[buf][(wv * 4 + j) * 512], 16, 0, 0);
        }
    };

    const int qg = qt * 64 + wv * 16 + lr;   // this lane's q row (column of S^T)

    short8 aq[4];
    {
        const unsigned short* qp = Q + ((size_t)h * S_LEN + qg) * HDIM + lgp * 8;
#pragma unroll
        for (int kk = 0; kk < 4; ++kk) aq[kk] = *(const short8*)(qp + kk * 32);
    }

    f32x4 oacc[8] = {};
    float m_i = -3.0e38f, l_i = 0.f;

    short8 vcur[4];
    stageK(0, 0);
    {
        const unsigned short* vp = Vg + lane * HDIM + wv * 32;
#pragma unroll
        for (int r2 = 0; r2 < 4; ++r2) vcur[r2] = *(const short8*)(vp + r2 * 8);
    }

#pragma unroll 1
    for (int kb = 0; kb <= qt; ++kb) {
        const int cur = kb & 1;
        __syncthreads();   // b1: prev PV reads of Vt done; drains prefetches
        // scatter V regs -> transposed swizzled Vt ([d][kv], ^((d&7)<<3))
#pragma unroll
        for (int r2 = 0; r2 < 4; ++r2) {
#pragma unroll
            for (int e = 0; e < 8; ++e) {
                int d = wv * 32 + r2 * 8 + e;
                Vt[(d * 64 + lane) ^ ((d & 7) << 3)] = ((const unsigned short*)&vcur[r2])[e];
            }
        }
        __syncthreads();   // b2: scatter visible

        if (kb < qt) {     // next tile's loads fly during compute
            stageK(cur ^ 1, kb + 1);
            const unsigned short* vp = Vg + (size_t)(kb + 1) * 64 * HDIM + lane * HDIM + wv * 32;
#pragma unroll
            for (int r2 = 0; r2 < 4; ++r2) vcur[r2] = *(const short8*)(vp + r2 * 8);
        }

        __builtin_amdgcn_s_setprio(1);
        // QK^T swapped: sc[nt2] rows = kv (nt2*16 + 4*lgp + i), cols = q (lr)
        f32x4 sc[4];
#pragma unroll
        for (int nt2 = 0; nt2 < 4; ++nt2) {
            f32x4 a = {};
            const int krow = nt2 * 16 + lr;
            const int swz = (krow & 7) << 3;
#pragma unroll
            for (int kk = 0; kk < 4; ++kk) {
                short8 ak = *(const short8*)&Ks[cur][(krow * 128 + kk * 32 + lgp * 8) ^ swz];
                a = __builtin_amdgcn_mfma_f32_16x16x32_bf16(ak, aq[kk], a, 0, 0, 0);
            }
            sc[nt2] = a;
        }
        __builtin_amdgcn_s_setprio(0);

        if (kb == qt) {    // causal mask (Q pre-scaled)
#pragma unroll
            for (int nt2 = 0; nt2 < 4; ++nt2)
#pragma unroll
                for (int i = 0; i < 4; ++i) {
                    int kvg = kb * 64 + nt2 * 16 + 4 * lgp + i;
                    if (kvg > qg) sc[nt2][i] = -1.0e30f;
                }
        }

        // in-register online softmax for q = lr
        float vmax = fmaxf(fmaxf(fmaxf(sc[0][0], sc[0][1]), fmaxf(sc[0][2], sc[0][3])),
                           fmaxf(fmaxf(sc[1][0], sc[1][1]), fmaxf(sc[1][2], sc[1][3])));
        vmax = fmaxf(vmax, fmaxf(fmaxf(fmaxf(sc[2][0], sc[2][1]), fmaxf(sc[2][2], sc[2][3])),
                                 fmaxf(fmaxf(sc[3][0], sc[3][1]), fmaxf(sc[3][2], sc[3][3]))));
        vmax = fmaxf(vmax, __shfl_xor(vmax, 16));
        vmax = fmaxf(vmax, __shfl_xor(vmax, 32));
        float mn = fmaxf(m_i, vmax);
        float fe = __expf(m_i - mn);
        m_i = mn;
        l_i *= fe;
        float rs = 0.f;
#pragma unroll
        for (int nt2 = 0; nt2 < 4; ++nt2)
#pragma unroll
            for (int i = 0; i < 4; ++i) {
                float pv = __expf(sc[nt2][i] - mn);
                sc[nt2][i] = pv;
                rs += pv;
            }
        rs += __shfl_xor(rs, 16);
        rs += __shfl_xor(rs, 32);
        l_i += rs;

        // rescale oacc rows (row q = 4*lgp + i2; fe lives at lane with lr == that q)
        float feb[4];
#pragma unroll
        for (int i2 = 0; i2 < 4; ++i2) feb[i2] = __shfl(fe, 4 * lgp + i2);
#pragma unroll
        for (int t = 0; t < 8; ++t)
#pragma unroll
            for (int i2 = 0; i2 < 4; ++i2) oacc[t][i2] *= feb[i2];

        // P (A-operand, permuted-k): slot i<4 -> sc[2kk][i], slot i>=4 -> sc[2kk+1][i-4]
        short8 ap[2];
#pragma unroll
        for (int kk = 0; kk < 2; ++kk)
#pragma unroll
            for (int j = 0; j < 4; ++j) {
                ap[kk][j]     = (short)f2bf(sc[2 * kk][j]);
                ap[kk][4 + j] = (short)f2bf(sc[2 * kk + 1][j]);
            }

        // PV: B = V^T fragments from Vt with the SAME permuted-k convention
        __builtin_amdgcn_s_setprio(1);
#pragma unroll
        for (int t = 0; t < 8; ++t) {
            const int d = t * 16 + lr;
            const int swz = (d & 7) << 3;
            const int dbase = d * 64;
#pragma unroll
            for (int kk = 0; kk < 2; ++kk) {
                short4v lo = *(const short4v*)&Vt[(dbase + kk * 32 + lgp * 4) ^ swz];
                short4v hi = *(const short4v*)&Vt[(dbase + kk * 32 + 16 + lgp * 4) ^ swz];
                short8 bv;
                bv[0] = lo[0]; bv[1] = lo[1]; bv[2] = lo[2]; bv[3] = lo[3];
                bv[4] = hi[0]; bv[5] = hi[1]; bv[6] = hi[2]; bv[7] = hi[3];
                oacc[t] = __builtin_amdgcn_mfma_f32_16x16x32_bf16(ap[kk], bv, oacc[t], 0, 0, 0);
            }
        }
        __builtin_amdgcn_s_setprio(0);
    }

    // epilogue: O[q][d], q = qt*64 + wv*16 + 4*lgp + i2, d = t*16 + lr
    float invb[4];
    {
        float inv = 1.0f / l_i;
#pragma unroll
        for (int i2 = 0; i2 < 4; ++i2) invb[i2] = __shfl(inv, 4 * lgp + i2);
    }
    float* ob = O + (size_t)(qt * 64 + wv * 16 + 4 * lgp) * HID + h * HDIM + lr;
#pragma unroll
    for (int t = 0; t < 8; ++t)
#pragma unroll
        for (int i2 = 0; i2 < 4; ++i2)
            ob[(size_t)i2 * HID + t * 16] = oacc[t][i2] * invb[i2];
}

// ---------------- launch ----------------
extern "C" void kernel_launch(void* const* d_in, const int* in_sizes, int n_in,
                              void* d_out, int out_size, void* d_ws, size_t ws_size,
                              hipStream_t stream) {
    const float* hidden = (const float*)d_in[0];
    const int*   pos    = (const int*)d_in[1];
    const float* su_qkv = (const float*)d_in[2];
    const float* su_o   = (const float*)d_in[3];
    const float* ws_qkv = (const float*)d_in[4];
    const float* ws_o   = (const float*)d_in[5];
    const float* Wq     = (const float*)d_in[6];
    const float* Wk     = (const float*)d_in[7];
    const float* Wv     = (const float*)d_in[8];
    const float* Wo     = (const float*)d_in[9];
    float* out = (float*)d_out;

    char* ws = (char*)d_ws;
    unsigned short* Wcat = (unsigned short*)(ws);                        // [6144][4096] bf16
    unsigned short* Wob  = (unsigned short*)(ws + 50331648);             // [4096][4096] bf16
    unsigned short* xb   = (unsigned short*)(ws + 83886080);             // [2048][4096] bf16 (reused as y_in)
    float*          qkv  = (float*)(ws + 100663296);                     // [2048][6144] f32 (reused as attn_out)
    unsigned short* Qb   = (unsigned short*)(ws + 150994944);            // [32][2048][128] bf16
    unsigned short* Kb   = Qb + (size_t)NHEAD * S_LEN * HDIM;
    unsigned short* Vb   = Kb + (size_t)NKVH * S_LEN * HDIM;
    float* attn_out = qkv;

    cvt_kernel<<<1024, 256, 0, stream>>>(Wq, Wcat, HID * HID);
    cvt_kernel<<<256, 256, 0, stream>>>(Wk, Wcat + (size_t)HID * HID, NKVH * HDIM * HID);
    cvt_kernel<<<256, 256, 0, stream>>>(Wv, Wcat + (size_t)(HID + NKVH * HDIM) * HID, NKVH * HDIM * HID);
    cvt_kernel<<<1024, 256, 0, stream>>>(Wo, Wob, HID * HID);

    fwht_kernel<<<S_LEN, 256, 0, stream>>>(hidden, su_qkv, xb);
    gemm_q<256><<<dim3((NQKV / 256) * (S_LEN / 256)), 512, 0, stream>>>(xb, Wcat, ws_qkv, qkv, S_LEN, NQKV, HID);
    rope_kernel<<<S_LEN, 256, 0, stream>>>(qkv, pos, Qb, Kb, Vb);
    attn_kernel<<<dim3(32, NHEAD), 256, 0, stream>>>(Qb, Kb, Vb, attn_out);
    fwht_kernel<<<S_LEN, 256, 0, stream>>>(attn_out, su_o, xb);
    gemm_q<128><<<dim3((HID / 256) * (S_LEN / 128)), 512, 0, stream>>>(xb, Wob, ws_o, out, S_LEN, HID, HID);
}

// Round 6
// 505.963 us; speedup vs baseline: 1.0670x; 1.0670x over previous
//
#include <hip/hip_runtime.h>
#include <hip/hip_bf16.h>
#include <math.h>

#define S_LEN 2048
#define HID   4096
#define NQKV  6144
#define NHEAD 32
#define NKVH  8
#define HDIM  128

typedef __attribute__((ext_vector_type(8))) short short8;
typedef __attribute__((ext_vector_type(4))) short short4v;
typedef __attribute__((ext_vector_type(4))) float f32x4;

__device__ __forceinline__ unsigned short f2bf(float f) {
    union { float f; unsigned u; } v; v.f = f;
    unsigned r = v.u + 0x7fffu + ((v.u >> 16) & 1u);
    return (unsigned short)(r >> 16);
}

// ---------------- fused fp32 -> bf16 convert of all four weight mats ----------------
__global__ __launch_bounds__(256)
void cvt4_kernel(const float* __restrict__ Wq, const float* __restrict__ Wk,
                 const float* __restrict__ Wv, const float* __restrict__ Wo,
                 unsigned short* __restrict__ Wcat, unsigned short* __restrict__ Wob) {
    const int NQ = 4194304, NK = 1048576, NV = 1048576, NO = 4194304; // float4 counts
    int i = blockIdx.x * 256 + threadIdx.x;
    const int stride = gridDim.x * 256;
    for (; i < NQ + NK + NV + NO; i += stride) {
        const float* src; unsigned short* dst; int j;
        if (i < NQ)                { src = Wq; dst = Wcat;            j = i; }
        else if (i < NQ + NK)      { src = Wk; dst = Wcat + 16777216; j = i - NQ; }
        else if (i < NQ + NK + NV) { src = Wv; dst = Wcat + 20971520; j = i - NQ - NK; }
        else                       { src = Wo; dst = Wob;             j = i - NQ - NK - NV; }
        float4 v = *(const float4*)(src + (size_t)j * 4);
        ushort4 o;
        o.x = f2bf(v.x); o.y = f2bf(v.y); o.z = f2bf(v.z); o.w = f2bf(v.w);
        *(ushort4*)(dst + (size_t)j * 4) = o;
    }
}

// ---------------- FWHT over 4096, * su, * 1/4096, -> bf16 ----------------
__global__ __launch_bounds__(256)
void fwht_kernel(const float* __restrict__ in, const float* __restrict__ su,
                 unsigned short* __restrict__ out) {
    __shared__ float buf[HID];
    const float* src = in + (size_t)blockIdx.x * HID;
    for (int i = threadIdx.x; i < HID; i += 256) buf[i] = src[i] * su[i];
    __syncthreads();
    int lg = 0;
    for (int h = 1; h < HID; h <<= 1, ++lg) {
        for (int p = threadIdx.x; p < HID / 2; p += 256) {
            int j  = p & (h - 1);
            int i0 = ((p >> lg) << (lg + 1)) | j;
            int i1 = i0 + h;
            float a = buf[i0], b = buf[i1];
            buf[i0] = a + b;
            buf[i1] = a - b;
        }
        __syncthreads();
    }
    unsigned short* dst = out + (size_t)blockIdx.x * HID;
    const float norm = 1.0f / 4096.0f;   // (1/sqrt(4096)) * (1/SCALE)
    for (int i = threadIdx.x; i < HID; i += 256) dst[i] = f2bf(buf[i] * norm);
}

// ---------------- bf16 GEMM (m97 128x128 structure, HW-verified ~870-910 TF) ----------------
// C[m][n] = (sum_k A[m][k]*B[n][k]) * scale[n] * 64
__global__ __launch_bounds__(256)
void gemm_bt(const unsigned short* __restrict__ A, const unsigned short* __restrict__ B,
             const float* __restrict__ scale, float* __restrict__ C,
             int M, int N, int K) {
    __shared__ __attribute__((aligned(16))) unsigned short As[2][128 * 32];
    __shared__ __attribute__((aligned(16))) unsigned short Bs[2][128 * 32];
    const int bn = blockIdx.x, bm = blockIdx.y;
    const int tid = threadIdx.x;
    const int wv = tid >> 6, lane = tid & 63;
    const int wr = wv >> 1, wc = wv & 1;
    const int lr = lane & 15, lgp = lane >> 4;

    f32x4 acc[4][4] = {};

    auto stage = [&](int buf, int kt) {
        for (int c = wv; c < 8; c += 4) {
            int o = c * 512 + lane * 8;
            int row = o >> 5, col = o & 31;
            const unsigned short* ga = A + (size_t)(bm * 128 + row) * K + kt * 32 + col;
            __builtin_amdgcn_global_load_lds((const __attribute__((address_space(1))) void*)ga,
                (__attribute__((address_space(3))) void*)&As[buf][c * 512], 16, 0, 0);
            const unsigned short* gb = B + (size_t)(bn * 128 + row) * K + kt * 32 + col;
            __builtin_amdgcn_global_load_lds((const __attribute__((address_space(1))) void*)gb,
                (__attribute__((address_space(3))) void*)&Bs[buf][c * 512], 16, 0, 0);
        }
    };

    const int nt = K >> 5;
    stage(0, 0);
    __syncthreads();
    int cur = 0;
    for (int kt = 0; kt < nt; ++kt) {
        if (kt + 1 < nt) stage(cur ^ 1, kt + 1);
        const int ko = lgp * 8;
        short8 af[4], bfr[4];
#pragma unroll
        for (int m2 = 0; m2 < 4; ++m2)
            af[m2] = *(const short8*)&As[cur][(wr * 64 + m2 * 16 + lr) * 32 + ko];
#pragma unroll
        for (int n2 = 0; n2 < 4; ++n2)
            bfr[n2] = *(const short8*)&Bs[cur][(wc * 64 + n2 * 16 + lr) * 32 + ko];
#pragma unroll
        for (int m2 = 0; m2 < 4; ++m2)
#pragma unroll
            for (int n2 = 0; n2 < 4; ++n2)
                acc[m2][n2] = __builtin_amdgcn_mfma_f32_16x16x32_bf16(af[m2], bfr[n2], acc[m2][n2], 0, 0, 0);
        __syncthreads();
        cur ^= 1;
    }

#pragma unroll
    for (int n2 = 0; n2 < 4; ++n2) {
        int gn = bn * 128 + wc * 64 + n2 * 16 + lr;
        float sc = scale[gn] * 64.0f;
#pragma unroll
        for (int m2 = 0; m2 < 4; ++m2) {
            int gm0 = bm * 128 + wr * 64 + m2 * 16 + lgp * 4;
#pragma unroll
            for (int i = 0; i < 4; ++i)
                C[(size_t)(gm0 + i) * N + gn] = acc[m2][n2][i] * sc;
        }
    }
}

// ---------------- RoPE + relayout to head-major bf16 Q/K/V ----------------
// Q is pre-scaled by 1/sqrt(HDIM) so attention skips the softmax scale.
__global__ __launch_bounds__(256)
void rope_kernel(const float* __restrict__ qkv, const int* __restrict__ pos,
                 unsigned short* __restrict__ Qb, unsigned short* __restrict__ Kb,
                 unsigned short* __restrict__ Vb) {
    const int s = blockIdx.x;
    const float p = (float)pos[s];
    const float* row = qkv + (size_t)s * NQKV;
    const float sm = 0.08838834764831845f;   // 1/sqrt(128)
    for (int idx = threadIdx.x; idx < NQKV; idx += 256) {
        float v = row[idx];
        if (idx < HID + NKVH * HDIM) {      // q or k -> RoPE
            int base = (idx < HID) ? 0 : HID;
            int rel = idx - base;
            int h = rel >> 7, d = rel & 127;
            int j = d & 63;
            float invf = expf((float)j * (-13.122363377404329f / 64.0f)); // theta^(-2j/128)
            float ang = p * invf;
            float sn, cs;
            sincosf(ang, &sn, &cs);
            float other = (d < 64) ? -row[base + h * 128 + d + 64]
                                   :  row[base + h * 128 + d - 64];
            float r = v * cs + other * sn;
            if (idx < HID) Qb[((size_t)h * S_LEN + s) * HDIM + d] = f2bf(r * sm);
            else           Kb[((size_t)h * S_LEN + s) * HDIM + d] = f2bf(r);
        } else {                             // v passthrough
            int rel = idx - (HID + NKVH * HDIM);
            int h = rel >> 7, d = rel & 127;
            Vb[((size_t)h * S_LEN + s) * HDIM + d] = f2bf(v);
        }
    }
}

// ---------------- causal GQA flash attention (swapped QK^T, in-reg softmax) ----------------
__global__ __launch_bounds__(256)
void attn_kernel(const unsigned short* __restrict__ Q, const unsigned short* __restrict__ K,
                 const unsigned short* __restrict__ V, float* __restrict__ O) {
    const int qt = 31 - (int)blockIdx.x;
    const int h  = blockIdx.y;
    const int kvh = h >> 2;
    const int tid = threadIdx.x, wv = tid >> 6, lane = tid & 63;
    const int lr = lane & 15, lgp = lane >> 4;

    __shared__ __attribute__((aligned(16))) unsigned short Ks[2][64 * 128];
    __shared__ __attribute__((aligned(16))) unsigned short Vt[128 * 64];

    int koff[4];
#pragma unroll
    for (int j = 0; j < 4; ++j) {
        int a = (wv * 4 + j) * 512 + lane * 8;
        koff[j] = a ^ (((a >> 7) & 7) << 3);
    }
    const unsigned short* Kg = K + (size_t)kvh * S_LEN * HDIM;
    const unsigned short* Vg = V + (size_t)kvh * S_LEN * HDIM;

    auto stageK = [&](int buf, int kb) {
        const unsigned short* kg = Kg + (size_t)kb * 64 * HDIM;
#pragma unroll
        for (int j = 0; j < 4; ++j) {
            __builtin_amdgcn_global_load_lds(
                (const __attribute__((address_space(1))) void*)(kg + koff[j]),
                (__attribute__((address_space(3))) void*)&Ks[buf][(wv * 4 + j) * 512], 16, 0, 0);
        }
    };

    const int qg = qt * 64 + wv * 16 + lr;   // this lane's q row (column of S^T)

    short8 aq[4];
    {
        const unsigned short* qp = Q + ((size_t)h * S_LEN + qg) * HDIM + lgp * 8;
#pragma unroll
        for (int kk = 0; kk < 4; ++kk) aq[kk] = *(const short8*)(qp + kk * 32);
    }

    f32x4 oacc[8] = {};
    float m_i = -3.0e38f, l_i = 0.f;

    short8 vcur[4];
    stageK(0, 0);
    {
        const unsigned short* vp = Vg + lane * HDIM + wv * 32;
#pragma unroll
        for (int r2 = 0; r2 < 4; ++r2) vcur[r2] = *(const short8*)(vp + r2 * 8);
    }

#pragma unroll 1
    for (int kb = 0; kb <= qt; ++kb) {
        const int cur = kb & 1;
        __syncthreads();   // b1: prev PV reads of Vt done; drains prefetches
        // scatter V regs -> transposed swizzled Vt ([d][kv], ^((d&7)<<3))
#pragma unroll
        for (int r2 = 0; r2 < 4; ++r2) {
#pragma unroll
            for (int e = 0; e < 8; ++e) {
                int d = wv * 32 + r2 * 8 + e;
                Vt[(d * 64 + lane) ^ ((d & 7) << 3)] = ((const unsigned short*)&vcur[r2])[e];
            }
        }
        __syncthreads();   // b2: scatter visible

        if (kb < qt) {     // next tile's loads fly during compute
            stageK(cur ^ 1, kb + 1);
            const unsigned short* vp = Vg + (size_t)(kb + 1) * 64 * HDIM + lane * HDIM + wv * 32;
#pragma unroll
            for (int r2 = 0; r2 < 4; ++r2) vcur[r2] = *(const short8*)(vp + r2 * 8);
        }

        __builtin_amdgcn_s_setprio(1);
        // QK^T swapped: sc[nt2] rows = kv (nt2*16 + 4*lgp + i), cols = q (lr)
        f32x4 sc[4];
#pragma unroll
        for (int nt2 = 0; nt2 < 4; ++nt2) {
            f32x4 a = {};
            const int krow = nt2 * 16 + lr;
            const int swz = (krow & 7) << 3;
#pragma unroll
            for (int kk = 0; kk < 4; ++kk) {
                short8 ak = *(const short8*)&Ks[cur][(krow * 128 + kk * 32 + lgp * 8) ^ swz];
                a = __builtin_amdgcn_mfma_f32_16x16x32_bf16(ak, aq[kk], a, 0, 0, 0);
            }
            sc[nt2] = a;
        }
        __builtin_amdgcn_s_setprio(0);

        if (kb == qt) {    // causal mask (Q pre-scaled)
#pragma unroll
            for (int nt2 = 0; nt2 < 4; ++nt2)
#pragma unroll
                for (int i = 0; i < 4; ++i) {
                    int kvg = kb * 64 + nt2 * 16 + 4 * lgp + i;
                    if (kvg > qg) sc[nt2][i] = -1.0e30f;
                }
        }

        // in-register online softmax for q = lr
        float vmax = fmaxf(fmaxf(fmaxf(sc[0][0], sc[0][1]), fmaxf(sc[0][2], sc[0][3])),
                           fmaxf(fmaxf(sc[1][0], sc[1][1]), fmaxf(sc[1][2], sc[1][3])));
        vmax = fmaxf(vmax, fmaxf(fmaxf(fmaxf(sc[2][0], sc[2][1]), fmaxf(sc[2][2], sc[2][3])),
                                 fmaxf(fmaxf(sc[3][0], sc[3][1]), fmaxf(sc[3][2], sc[3][3]))));
        vmax = fmaxf(vmax, __shfl_xor(vmax, 16));
        vmax = fmaxf(vmax, __shfl_xor(vmax, 32));
        float mn = fmaxf(m_i, vmax);
        float fe = __expf(m_i - mn);
        m_i = mn;
        l_i *= fe;
        float rs = 0.f;
#pragma unroll
        for (int nt2 = 0; nt2 < 4; ++nt2)
#pragma unroll
            for (int i = 0; i < 4; ++i) {
                float pv = __expf(sc[nt2][i] - mn);
                sc[nt2][i] = pv;
                rs += pv;
            }
        rs += __shfl_xor(rs, 16);
        rs += __shfl_xor(rs, 32);
        l_i += rs;

        // rescale oacc rows (row q = 4*lgp + i2; fe lives at lane with lr == that q)
        float feb[4];
#pragma unroll
        for (int i2 = 0; i2 < 4; ++i2) feb[i2] = __shfl(fe, 4 * lgp + i2);
#pragma unroll
        for (int t = 0; t < 8; ++t)
#pragma unroll
            for (int i2 = 0; i2 < 4; ++i2) oacc[t][i2] *= feb[i2];

        // P (A-operand, permuted-k): slot i<4 -> sc[2kk][i], slot i>=4 -> sc[2kk+1][i-4]
        short8 ap[2];
#pragma unroll
        for (int kk = 0; kk < 2; ++kk)
#pragma unroll
            for (int j = 0; j < 4; ++j) {
                ap[kk][j]     = (short)f2bf(sc[2 * kk][j]);
                ap[kk][4 + j] = (short)f2bf(sc[2 * kk + 1][j]);
            }

        // PV: B = V^T fragments from Vt with the SAME permuted-k convention
        __builtin_amdgcn_s_setprio(1);
#pragma unroll
        for (int t = 0; t < 8; ++t) {
            const int d = t * 16 + lr;
            const int swz = (d & 7) << 3;
            const int dbase = d * 64;
#pragma unroll
            for (int kk = 0; kk < 2; ++kk) {
                short4v lo = *(const short4v*)&Vt[(dbase + kk * 32 + lgp * 4) ^ swz];
                short4v hi = *(const short4v*)&Vt[(dbase + kk * 32 + 16 + lgp * 4) ^ swz];
                short8 bv;
                bv[0] = lo[0]; bv[1] = lo[1]; bv[2] = lo[2]; bv[3] = lo[3];
                bv[4] = hi[0]; bv[5] = hi[1]; bv[6] = hi[2]; bv[7] = hi[3];
                oacc[t] = __builtin_amdgcn_mfma_f32_16x16x32_bf16(ap[kk], bv, oacc[t], 0, 0, 0);
            }
        }
        __builtin_amdgcn_s_setprio(0);
    }

    // epilogue: O[q][d], q = qt*64 + wv*16 + 4*lgp + i2, d = t*16 + lr
    float invb[4];
    {
        float inv = 1.0f / l_i;
#pragma unroll
        for (int i2 = 0; i2 < 4; ++i2) invb[i2] = __shfl(inv, 4 * lgp + i2);
    }
    float* ob = O + (size_t)(qt * 64 + wv * 16 + 4 * lgp) * HID + h * HDIM + lr;
#pragma unroll
    for (int t = 0; t < 8; ++t)
#pragma unroll
        for (int i2 = 0; i2 < 4; ++i2)
            ob[(size_t)i2 * HID + t * 16] = oacc[t][i2] * invb[i2];
}

// ---------------- launch ----------------
extern "C" void kernel_launch(void* const* d_in, const int* in_sizes, int n_in,
                              void* d_out, int out_size, void* d_ws, size_t ws_size,
                              hipStream_t stream) {
    const float* hidden = (const float*)d_in[0];
    const int*   pos    = (const int*)d_in[1];
    const float* su_qkv = (const float*)d_in[2];
    const float* su_o   = (const float*)d_in[3];
    const float* ws_qkv = (const float*)d_in[4];
    const float* ws_o   = (const float*)d_in[5];
    const float* Wq     = (const float*)d_in[6];
    const float* Wk     = (const float*)d_in[7];
    const float* Wv     = (const float*)d_in[8];
    const float* Wo     = (const float*)d_in[9];
    float* out = (float*)d_out;

    char* ws = (char*)d_ws;
    unsigned short* Wcat = (unsigned short*)(ws);                        // [6144][4096] bf16
    unsigned short* Wob  = (unsigned short*)(ws + 50331648);             // [4096][4096] bf16
    unsigned short* xb   = (unsigned short*)(ws + 83886080);             // [2048][4096] bf16 (reused as y_in)
    float*          qkv  = (float*)(ws + 100663296);                     // [2048][6144] f32 (reused as attn_out)
    unsigned short* Qb   = (unsigned short*)(ws + 150994944);            // [32][2048][128] bf16
    unsigned short* Kb   = Qb + (size_t)NHEAD * S_LEN * HDIM;
    unsigned short* Vb   = Kb + (size_t)NKVH * S_LEN * HDIM;
    float* attn_out = qkv;

    cvt4_kernel<<<2560, 256, 0, stream>>>(Wq, Wk, Wv, Wo, Wcat, Wob);

    fwht_kernel<<<S_LEN, 256, 0, stream>>>(hidden, su_qkv, xb);
    gemm_bt<<<dim3(NQKV / 128, S_LEN / 128), 256, 0, stream>>>(xb, Wcat, ws_qkv, qkv, S_LEN, NQKV, HID);
    rope_kernel<<<S_LEN, 256, 0, stream>>>(qkv, pos, Qb, Kb, Vb);
    attn_kernel<<<dim3(32, NHEAD), 256, 0, stream>>>(Qb, Kb, Vb, attn_out);
    fwht_kernel<<<S_LEN, 256, 0, stream>>>(attn_out, su_o, xb);
    gemm_bt<<<dim3(HID / 128, S_LEN / 128), 256, 0, stream>>>(xb, Wob, ws_o, out, S_LEN, HID, HID);
}

// Round 7
// 489.208 us; speedup vs baseline: 1.1036x; 1.0342x over previous
//
#include <hip/hip_runtime.h>
#include <hip/hip_bf16.h>
#include <math.h>

#define S_LEN 2048
#define HID   4096
#define NQKV  6144
#define NHEAD 32
#define NKVH  8
#define HDIM  128

typedef __attribute__((ext_vector_type(8))) short short8;
typedef __attribute__((ext_vector_type(4))) float f32x4;

__device__ __forceinline__ unsigned short f2bf(float f) {
    union { float f; unsigned u; } v; v.f = f;
    unsigned r = v.u + 0x7fffu + ((v.u >> 16) & 1u);
    return (unsigned short)(r >> 16);
}

__device__ __forceinline__ unsigned cvt_pk_bf16(float lo, float hi) {
    unsigned r;
    asm("v_cvt_pk_bf16_f32 %0, %1, %2" : "=v"(r) : "v"(lo), "v"(hi));
    return r;
}

// ---------------- fused fp32 -> bf16 convert of all four weight mats ----------------
__global__ __launch_bounds__(256)
void cvt4_kernel(const float* __restrict__ Wq, const float* __restrict__ Wk,
                 const float* __restrict__ Wv, const float* __restrict__ Wo,
                 unsigned short* __restrict__ Wcat, unsigned short* __restrict__ Wob) {
    const int NQ = 4194304, NK = 1048576, NV = 1048576, NO = 4194304; // float4 counts
    int i = blockIdx.x * 256 + threadIdx.x;
    const int stride = gridDim.x * 256;
    for (; i < NQ + NK + NV + NO; i += stride) {
        const float* src; unsigned short* dst; int j;
        if (i < NQ)                { src = Wq; dst = Wcat;            j = i; }
        else if (i < NQ + NK)      { src = Wk; dst = Wcat + 16777216; j = i - NQ; }
        else if (i < NQ + NK + NV) { src = Wv; dst = Wcat + 20971520; j = i - NQ - NK; }
        else                       { src = Wo; dst = Wob;             j = i - NQ - NK - NV; }
        float4 v = *(const float4*)(src + (size_t)j * 4);
        ushort4 o;
        o.x = f2bf(v.x); o.y = f2bf(v.y); o.z = f2bf(v.z); o.w = f2bf(v.w);
        *(ushort4*)(dst + (size_t)j * 4) = o;
    }
}

// ---------------- FWHT over 4096, * su, * 1/4096, -> bf16 ----------------
__global__ __launch_bounds__(256)
void fwht_kernel(const float* __restrict__ in, const float* __restrict__ su,
                 unsigned short* __restrict__ out) {
    __shared__ float buf[HID];
    const float* src = in + (size_t)blockIdx.x * HID;
    for (int i = threadIdx.x; i < HID; i += 256) buf[i] = src[i] * su[i];
    __syncthreads();
    int lg = 0;
    for (int h = 1; h < HID; h <<= 1, ++lg) {
        for (int p = threadIdx.x; p < HID / 2; p += 256) {
            int j  = p & (h - 1);
            int i0 = ((p >> lg) << (lg + 1)) | j;
            int i1 = i0 + h;
            float a = buf[i0], b = buf[i1];
            buf[i0] = a + b;
            buf[i1] = a - b;
        }
        __syncthreads();
    }
    unsigned short* dst = out + (size_t)blockIdx.x * HID;
    const float norm = 1.0f / 4096.0f;   // (1/sqrt(4096)) * (1/SCALE)
    for (int i = threadIdx.x; i < HID; i += 256) dst[i] = f2bf(buf[i] * norm);
}

// ---------------- bf16 GEMM (m97 128x128 structure, HW-verified ~870-910 TF) ----------------
// C[m][n] = (sum_k A[m][k]*B[n][k]) * scale[n] * 64
__global__ __launch_bounds__(256)
void gemm_bt(const unsigned short* __restrict__ A, const unsigned short* __restrict__ B,
             const float* __restrict__ scale, float* __restrict__ C,
             int M, int N, int K) {
    __shared__ __attribute__((aligned(16))) unsigned short As[2][128 * 32];
    __shared__ __attribute__((aligned(16))) unsigned short Bs[2][128 * 32];
    const int bn = blockIdx.x, bm = blockIdx.y;
    const int tid = threadIdx.x;
    const int wv = tid >> 6, lane = tid & 63;
    const int wr = wv >> 1, wc = wv & 1;
    const int lr = lane & 15, lgp = lane >> 4;

    f32x4 acc[4][4] = {};

    auto stage = [&](int buf, int kt) {
        for (int c = wv; c < 8; c += 4) {
            int o = c * 512 + lane * 8;
            int row = o >> 5, col = o & 31;
            const unsigned short* ga = A + (size_t)(bm * 128 + row) * K + kt * 32 + col;
            __builtin_amdgcn_global_load_lds((const __attribute__((address_space(1))) void*)ga,
                (__attribute__((address_space(3))) void*)&As[buf][c * 512], 16, 0, 0);
            const unsigned short* gb = B + (size_t)(bn * 128 + row) * K + kt * 32 + col;
            __builtin_amdgcn_global_load_lds((const __attribute__((address_space(1))) void*)gb,
                (__attribute__((address_space(3))) void*)&Bs[buf][c * 512], 16, 0, 0);
        }
    };

    const int nt = K >> 5;
    stage(0, 0);
    __syncthreads();
    int cur = 0;
    for (int kt = 0; kt < nt; ++kt) {
        if (kt + 1 < nt) stage(cur ^ 1, kt + 1);
        const int ko = lgp * 8;
        short8 af[4], bfr[4];
#pragma unroll
        for (int m2 = 0; m2 < 4; ++m2)
            af[m2] = *(const short8*)&As[cur][(wr * 64 + m2 * 16 + lr) * 32 + ko];
#pragma unroll
        for (int n2 = 0; n2 < 4; ++n2)
            bfr[n2] = *(const short8*)&Bs[cur][(wc * 64 + n2 * 16 + lr) * 32 + ko];
#pragma unroll
        for (int m2 = 0; m2 < 4; ++m2)
#pragma unroll
            for (int n2 = 0; n2 < 4; ++n2)
                acc[m2][n2] = __builtin_amdgcn_mfma_f32_16x16x32_bf16(af[m2], bfr[n2], acc[m2][n2], 0, 0, 0);
        __syncthreads();
        cur ^= 1;
    }

#pragma unroll
    for (int n2 = 0; n2 < 4; ++n2) {
        int gn = bn * 128 + wc * 64 + n2 * 16 + lr;
        float sc = scale[gn] * 64.0f;
#pragma unroll
        for (int m2 = 0; m2 < 4; ++m2) {
            int gm0 = bm * 128 + wr * 64 + m2 * 16 + lgp * 4;
#pragma unroll
            for (int i = 0; i < 4; ++i)
                C[(size_t)(gm0 + i) * N + gn] = acc[m2][n2][i] * sc;
        }
    }
}

// ---------------- RoPE + relayout to head-major bf16 Q/K/V ----------------
// Q is pre-scaled by log2(e)/sqrt(HDIM): attention runs softmax in exp2 domain.
__global__ __launch_bounds__(256)
void rope_kernel(const float* __restrict__ qkv, const int* __restrict__ pos,
                 unsigned short* __restrict__ Qb, unsigned short* __restrict__ Kb,
                 unsigned short* __restrict__ Vb) {
    __shared__ float invf_t[64];
    if (threadIdx.x < 64)
        invf_t[threadIdx.x] = exp2f((float)threadIdx.x * -0.29580576f); // theta^(-j/64), log2(5e5)/64
    __syncthreads();
    const int s = blockIdx.x;
    const float p = (float)pos[s];
    const float* row = qkv + (size_t)s * NQKV;
    const float qs = 0.12751793f;   // (1/sqrt(128)) * log2(e)
    for (int idx = threadIdx.x; idx < NQKV; idx += 256) {
        float v = row[idx];
        if (idx < HID + NKVH * HDIM) {      // q or k -> RoPE
            int base = (idx < HID) ? 0 : HID;
            int rel = idx - base;
            int h = rel >> 7, d = rel & 127;
            float ang = p * invf_t[d & 63];
            float sn, cs;
            sincosf(ang, &sn, &cs);
            float other = (d < 64) ? -row[base + h * 128 + d + 64]
                                   :  row[base + h * 128 + d - 64];
            float r = v * cs + other * sn;
            if (idx < HID) Qb[((size_t)h * S_LEN + s) * HDIM + d] = f2bf(r * qs);
            else           Kb[((size_t)h * S_LEN + s) * HDIM + d] = f2bf(r);
        } else {                             // v passthrough
            int rel = idx - (HID + NKVH * HDIM);
            int h = rel >> 7, d = rel & 127;
            Vb[((size_t)h * S_LEN + s) * HDIM + d] = f2bf(v);
        }
    }
}

// ---------------- causal GQA flash attention ----------------
// grid (16, 32): block x handles q-tiles x and 31-x (33 kv-iters each, balanced).
// Swapped QK^T (scores transposed, lane owns q-row lr) -> in-register softmax.
// exp2-domain (log2e folded into Q). Vt column-permuted so PV B-fragments are
// single ds_read_b128. Defer-max skips rescale on non-growing tiles.
__global__ __launch_bounds__(256)
void attn_kernel(const unsigned short* __restrict__ Q, const unsigned short* __restrict__ K,
                 const unsigned short* __restrict__ V, float* __restrict__ O) {
    const int h  = blockIdx.y;
    const int kvh = h >> 2;
    const int tid = threadIdx.x, wv = tid >> 6, lane = tid & 63;
    const int lr = lane & 15, lgp = lane >> 4;

    __shared__ __attribute__((aligned(16))) unsigned short Ks[2][64 * 128];
    __shared__ __attribute__((aligned(16))) unsigned short Vt[128 * 64];

    int koff[4];
#pragma unroll
    for (int j = 0; j < 4; ++j) {
        int a = (wv * 4 + j) * 512 + lane * 8;
        koff[j] = a ^ (((a >> 7) & 7) << 3);
    }
    // column permutation for Vt: pos(kv) groups A-side k-slot order contiguously
    const int vpos = ((lane >> 2) & 3) * 16 + (lane >> 4) * 4 + (lane & 3);
    const unsigned short* Kg = K + (size_t)kvh * S_LEN * HDIM;
    const unsigned short* Vg = V + (size_t)kvh * S_LEN * HDIM;

    auto stageK = [&](int buf, int kb) {
        const unsigned short* kg = Kg + (size_t)kb * 64 * HDIM;
#pragma unroll
        for (int j = 0; j < 4; ++j) {
            __builtin_amdgcn_global_load_lds(
                (const __attribute__((address_space(1))) void*)(kg + koff[j]),
                (__attribute__((address_space(3))) void*)&Ks[buf][(wv * 4 + j) * 512], 16, 0, 0);
        }
    };

#pragma unroll 1
    for (int rep = 0; rep < 2; ++rep) {
        const int qt = rep ? (31 - (int)blockIdx.x) : (int)blockIdx.x;
        const int qg = qt * 64 + wv * 16 + lr;   // this lane's q row

        __syncthreads();   // LDS reuse guard across reps

        short8 aq[4];
        {
            const unsigned short* qp = Q + ((size_t)h * S_LEN + qg) * HDIM + lgp * 8;
#pragma unroll
            for (int kk = 0; kk < 4; ++kk) aq[kk] = *(const short8*)(qp + kk * 32);
        }

        f32x4 oacc[8] = {};
        float m_i = -3.0e38f, l_i = 0.f;

        short8 vcur[4];
        stageK(0, 0);
        {
            const unsigned short* vp = Vg + lane * HDIM + wv * 32;
#pragma unroll
            for (int r2 = 0; r2 < 4; ++r2) vcur[r2] = *(const short8*)(vp + r2 * 8);
        }

#pragma unroll 1
        for (int kb = 0; kb <= qt; ++kb) {
            const int cur = kb & 1;
            __syncthreads();   // prev PV reads done; drains K gload + vcur loads
            // scatter V regs -> permuted+swizzled Vt[d][pos]
#pragma unroll
            for (int r2 = 0; r2 < 4; ++r2) {
#pragma unroll
                for (int e = 0; e < 8; ++e) {
                    int d = wv * 32 + r2 * 8 + e;
                    Vt[(d * 64 + vpos) ^ ((d & 7) << 3)] = ((const unsigned short*)&vcur[r2])[e];
                }
            }
            __syncthreads();   // scatter visible

            if (kb < qt) {     // next tile's loads fly during compute
                stageK(cur ^ 1, kb + 1);
                const unsigned short* vp = Vg + (size_t)(kb + 1) * 64 * HDIM + lane * HDIM + wv * 32;
#pragma unroll
                for (int r2 = 0; r2 < 4; ++r2) vcur[r2] = *(const short8*)(vp + r2 * 8);
            }

            __builtin_amdgcn_s_setprio(1);
            // QK^T swapped: sc[nt2] rows = kv (nt2*16 + 4*lgp + i), cols = q (lr)
            f32x4 sc[4];
#pragma unroll
            for (int nt2 = 0; nt2 < 4; ++nt2) {
                f32x4 a = {};
                const int krow = nt2 * 16 + lr;
                const int swz = (krow & 7) << 3;
#pragma unroll
                for (int kk = 0; kk < 4; ++kk) {
                    short8 ak = *(const short8*)&Ks[cur][(krow * 128 + kk * 32 + lgp * 8) ^ swz];
                    a = __builtin_amdgcn_mfma_f32_16x16x32_bf16(ak, aq[kk], a, 0, 0, 0);
                }
                sc[nt2] = a;
            }
            __builtin_amdgcn_s_setprio(0);

            if (kb == qt) {    // causal mask
#pragma unroll
                for (int nt2 = 0; nt2 < 4; ++nt2)
#pragma unroll
                    for (int i = 0; i < 4; ++i) {
                        int kvg = kb * 64 + nt2 * 16 + 4 * lgp + i;
                        if (kvg > qg) sc[nt2][i] = -1.0e30f;
                    }
            }

            // in-register online softmax (exp2 domain) for q = lr
            float vmax = fmaxf(fmaxf(fmaxf(sc[0][0], sc[0][1]), fmaxf(sc[0][2], sc[0][3])),
                               fmaxf(fmaxf(sc[1][0], sc[1][1]), fmaxf(sc[1][2], sc[1][3])));
            vmax = fmaxf(vmax, fmaxf(fmaxf(fmaxf(sc[2][0], sc[2][1]), fmaxf(sc[2][2], sc[2][3])),
                                     fmaxf(fmaxf(sc[3][0], sc[3][1]), fmaxf(sc[3][2], sc[3][3]))));
            vmax = fmaxf(vmax, __shfl_xor(vmax, 16));
            vmax = fmaxf(vmax, __shfl_xor(vmax, 32));

            if (!__all(vmax <= m_i + 11.0f)) {   // defer-max: P bounded by 2^11
                float mn = fmaxf(m_i, vmax);
                float fe = __builtin_amdgcn_exp2f(m_i - mn);
                m_i = mn;
                l_i *= fe;
                float feb[4];
#pragma unroll
                for (int i2 = 0; i2 < 4; ++i2) feb[i2] = __shfl(fe, 4 * lgp + i2);
#pragma unroll
                for (int t = 0; t < 8; ++t)
#pragma unroll
                    for (int i2 = 0; i2 < 4; ++i2) oacc[t][i2] *= feb[i2];
            }

            float rs = 0.f;
#pragma unroll
            for (int nt2 = 0; nt2 < 4; ++nt2)
#pragma unroll
                for (int i = 0; i < 4; ++i) {
                    float pv = __builtin_amdgcn_exp2f(sc[nt2][i] - m_i);
                    sc[nt2][i] = pv;
                    rs += pv;
                }
            rs += __shfl_xor(rs, 16);
            rs += __shfl_xor(rs, 32);
            l_i += rs;

            // P pack via v_cvt_pk_bf16_f32 (A-operand, permuted-k convention)
            union { unsigned u[4]; short8 s; } a0, a1;
            a0.u[0] = cvt_pk_bf16(sc[0][0], sc[0][1]);
            a0.u[1] = cvt_pk_bf16(sc[0][2], sc[0][3]);
            a0.u[2] = cvt_pk_bf16(sc[1][0], sc[1][1]);
            a0.u[3] = cvt_pk_bf16(sc[1][2], sc[1][3]);
            a1.u[0] = cvt_pk_bf16(sc[2][0], sc[2][1]);
            a1.u[1] = cvt_pk_bf16(sc[2][2], sc[2][3]);
            a1.u[2] = cvt_pk_bf16(sc[3][0], sc[3][1]);
            a1.u[3] = cvt_pk_bf16(sc[3][2], sc[3][3]);

            // PV: B fragments are contiguous b128 reads from permuted Vt
            __builtin_amdgcn_s_setprio(1);
#pragma unroll
            for (int t = 0; t < 8; ++t) {
                const int d = t * 16 + lr;
                const int swz = (d & 7) << 3;
                const int dbase = d * 64 + lgp * 16;
                short8 bv0 = *(const short8*)&Vt[(dbase) ^ swz];
                short8 bv1 = *(const short8*)&Vt[(dbase + 8) ^ swz];
                oacc[t] = __builtin_amdgcn_mfma_f32_16x16x32_bf16(a0.s, bv0, oacc[t], 0, 0, 0);
                oacc[t] = __builtin_amdgcn_mfma_f32_16x16x32_bf16(a1.s, bv1, oacc[t], 0, 0, 0);
            }
            __builtin_amdgcn_s_setprio(0);
        }

        // epilogue: O[q][d], q = qt*64 + wv*16 + 4*lgp + i2, d = t*16 + lr
        float invb[4];
        {
            float inv = 1.0f / l_i;
#pragma unroll
            for (int i2 = 0; i2 < 4; ++i2) invb[i2] = __shfl(inv, 4 * lgp + i2);
        }
        float* ob = O + (size_t)(qt * 64 + wv * 16 + 4 * lgp) * HID + h * HDIM + lr;
#pragma unroll
        for (int t = 0; t < 8; ++t)
#pragma unroll
            for (int i2 = 0; i2 < 4; ++i2)
                ob[(size_t)i2 * HID + t * 16] = oacc[t][i2] * invb[i2];
    }
}

// ---------------- launch ----------------
extern "C" void kernel_launch(void* const* d_in, const int* in_sizes, int n_in,
                              void* d_out, int out_size, void* d_ws, size_t ws_size,
                              hipStream_t stream) {
    const float* hidden = (const float*)d_in[0];
    const int*   pos    = (const int*)d_in[1];
    const float* su_qkv = (const float*)d_in[2];
    const float* su_o   = (const float*)d_in[3];
    const float* ws_qkv = (const float*)d_in[4];
    const float* ws_o   = (const float*)d_in[5];
    const float* Wq     = (const float*)d_in[6];
    const float* Wk     = (const float*)d_in[7];
    const float* Wv     = (const float*)d_in[8];
    const float* Wo     = (const float*)d_in[9];
    float* out = (float*)d_out;

    char* ws = (char*)d_ws;
    unsigned short* Wcat = (unsigned short*)(ws);                        // [6144][4096] bf16
    unsigned short* Wob  = (unsigned short*)(ws + 50331648);             // [4096][4096] bf16
    unsigned short* xb   = (unsigned short*)(ws + 83886080);             // [2048][4096] bf16 (reused as y_in)
    float*          qkv  = (float*)(ws + 100663296);                     // [2048][6144] f32 (reused as attn_out)
    unsigned short* Qb   = (unsigned short*)(ws + 150994944);            // [32][2048][128] bf16
    unsigned short* Kb   = Qb + (size_t)NHEAD * S_LEN * HDIM;
    unsigned short* Vb   = Kb + (size_t)NKVH * S_LEN * HDIM;
    float* attn_out = qkv;

    cvt4_kernel<<<2560, 256, 0, stream>>>(Wq, Wk, Wv, Wo, Wcat, Wob);

    fwht_kernel<<<S_LEN, 256, 0, stream>>>(hidden, su_qkv, xb);
    gemm_bt<<<dim3(NQKV / 128, S_LEN / 128), 256, 0, stream>>>(xb, Wcat, ws_qkv, qkv, S_LEN, NQKV, HID);
    rope_kernel<<<S_LEN, 256, 0, stream>>>(qkv, pos, Qb, Kb, Vb);
    attn_kernel<<<dim3(16, NHEAD), 256, 0, stream>>>(Qb, Kb, Vb, attn_out);
    fwht_kernel<<<S_LEN, 256, 0, stream>>>(attn_out, su_o, xb);
    gemm_bt<<<dim3(HID / 128, S_LEN / 128), 256, 0, stream>>>(xb, Wob, ws_o, out, S_LEN, HID, HID);
}

// Round 9
// 433.570 us; speedup vs baseline: 1.2452x; 1.1283x over previous
//
#include <hip/hip_runtime.h>
#include <hip/hip_bf16.h>
#include <math.h>

#define S_LEN 2048
#define HID   4096
#define NQKV  6144
#define NHEAD 32
#define NKVH  8
#define HDIM  128

typedef __attribute__((ext_vector_type(8))) short short8;
typedef __attribute__((ext_vector_type(4))) float f32x4;

__device__ __forceinline__ unsigned short f2bf(float f) {
    union { float f; unsigned u; } v; v.f = f;
    unsigned r = v.u + 0x7fffu + ((v.u >> 16) & 1u);
    return (unsigned short)(r >> 16);
}
__device__ __forceinline__ float bf2f(unsigned short b) {
    union { unsigned u; float f; } v; v.u = ((unsigned)b) << 16;
    return v.f;
}
__device__ __forceinline__ unsigned cvt_pk_bf16(float lo, float hi) {
    unsigned r;
    asm("v_cvt_pk_bf16_f32 %0, %1, %2" : "=v"(r) : "v"(lo), "v"(hi));
    return r;
}

// ---------------- fused fp32 -> bf16 convert of all four weight mats ----------------
__global__ __launch_bounds__(256)
void cvt4_kernel(const float* __restrict__ Wq, const float* __restrict__ Wk,
                 const float* __restrict__ Wv, const float* __restrict__ Wo,
                 unsigned short* __restrict__ Wcat, unsigned short* __restrict__ Wob) {
    const int NQ = 4194304, NK = 1048576, NV = 1048576, NO = 4194304; // float4 counts
    int i = blockIdx.x * 256 + threadIdx.x;
    const int stride = gridDim.x * 256;
    for (; i < NQ + NK + NV + NO; i += stride) {
        const float* src; unsigned short* dst; int j;
        if (i < NQ)                { src = Wq; dst = Wcat;            j = i; }
        else if (i < NQ + NK)      { src = Wk; dst = Wcat + 16777216; j = i - NQ; }
        else if (i < NQ + NK + NV) { src = Wv; dst = Wcat + 20971520; j = i - NQ - NK; }
        else                       { src = Wo; dst = Wob;             j = i - NQ - NK - NV; }
        float4 v = *(const float4*)(src + (size_t)j * 4);
        ushort4 o;
        o.x = f2bf(v.x); o.y = f2bf(v.y); o.z = f2bf(v.z); o.w = f2bf(v.w);
        *(ushort4*)(dst + (size_t)j * 4) = o;
    }
}

// ---------------- FWHT over 4096, * su, * 1/4096, -> bf16 ----------------
__global__ __launch_bounds__(256)
void fwht_kernel(const float* __restrict__ in, const float* __restrict__ su,
                 unsigned short* __restrict__ out) {
    __shared__ float buf[HID];
    const float* src = in + (size_t)blockIdx.x * HID;
    for (int i = threadIdx.x; i < HID; i += 256) buf[i] = src[i] * su[i];
    __syncthreads();
    int lg = 0;
    for (int h = 1; h < HID; h <<= 1, ++lg) {
        for (int p = threadIdx.x; p < HID / 2; p += 256) {
            int j  = p & (h - 1);
            int i0 = ((p >> lg) << (lg + 1)) | j;
            int i1 = i0 + h;
            float a = buf[i0], b = buf[i1];
            buf[i0] = a + b;
            buf[i1] = a - b;
        }
        __syncthreads();
    }
    unsigned short* dst = out + (size_t)blockIdx.x * HID;
    const float norm = 1.0f / 4096.0f;   // (1/sqrt(4096)) * (1/SCALE)
    for (int i = threadIdx.x; i < HID; i += 256) dst[i] = f2bf(buf[i] * norm);
}

// ---------------- merge split-KV partials + FWHT + *su/4096 -> bf16 ----------------
// O_final[q] = (e1*O1~ + e2*O2~) / (e1*l1 + e2*l2), e_h = 2^(m_h - max)
__global__ __launch_bounds__(256)
void fwht_merge(const unsigned short* __restrict__ O1, const float* __restrict__ ML,
                const float* __restrict__ su, unsigned short* __restrict__ out) {
    __shared__ float buf[HID];
    __shared__ float w1s[NHEAD], w2s[NHEAD];
    const int q = blockIdx.x;
    if (threadIdx.x < NHEAD) {
        const float2* mlp = (const float2*)ML;
        float2 a = mlp[((size_t)q) * NHEAD + threadIdx.x];
        float2 b = mlp[((size_t)(S_LEN + q)) * NHEAD + threadIdx.x];
        float M = fmaxf(a.x, b.x);
        float e1 = exp2f(a.x - M), e2 = exp2f(b.x - M);
        float L = e1 * a.y + e2 * b.y;
        w1s[threadIdx.x] = e1 / L;
        w2s[threadIdx.x] = e2 / L;
    }
    __syncthreads();
    const unsigned short* r1 = O1 + (size_t)q * HID;
    const unsigned short* r2 = O1 + (size_t)(S_LEN + q) * HID;
    for (int i = threadIdx.x; i < HID; i += 256) {
        int hd = i >> 7;
        buf[i] = (bf2f(r1[i]) * w1s[hd] + bf2f(r2[i]) * w2s[hd]) * su[i];
    }
    __syncthreads();
    int lg = 0;
    for (int h = 1; h < HID; h <<= 1, ++lg) {
        for (int p = threadIdx.x; p < HID / 2; p += 256) {
            int j  = p & (h - 1);
            int i0 = ((p >> lg) << (lg + 1)) | j;
            int i1 = i0 + h;
            float a = buf[i0], b = buf[i1];
            buf[i0] = a + b;
            buf[i1] = a - b;
        }
        __syncthreads();
    }
    unsigned short* dst = out + (size_t)q * HID;
    const float norm = 1.0f / 4096.0f;
    for (int i = threadIdx.x; i < HID; i += 256) dst[i] = f2bf(buf[i] * norm);
}

// ---------------- bf16 GEMM (m97 128x128 structure, HW-verified ~870-910 TF) ----------------
// C[m][n] = (sum_k A[m][k]*B[n][k]) * scale[n] * 64
__global__ __launch_bounds__(256)
void gemm_bt(const unsigned short* __restrict__ A, const unsigned short* __restrict__ B,
             const float* __restrict__ scale, float* __restrict__ C,
             int M, int N, int K) {
    __shared__ __attribute__((aligned(16))) unsigned short As[2][128 * 32];
    __shared__ __attribute__((aligned(16))) unsigned short Bs[2][128 * 32];
    const int bn = blockIdx.x, bm = blockIdx.y;
    const int tid = threadIdx.x;
    const int wv = tid >> 6, lane = tid & 63;
    const int wr = wv >> 1, wc = wv & 1;
    const int lr = lane & 15, lgp = lane >> 4;

    f32x4 acc[4][4] = {};

    auto stage = [&](int buf, int kt) {
        for (int c = wv; c < 8; c += 4) {
            int o = c * 512 + lane * 8;
            int row = o >> 5, col = o & 31;
            const unsigned short* ga = A + (size_t)(bm * 128 + row) * K + kt * 32 + col;
            __builtin_amdgcn_global_load_lds((const __attribute__((address_space(1))) void*)ga,
                (__attribute__((address_space(3))) void*)&As[buf][c * 512], 16, 0, 0);
            const unsigned short* gb = B + (size_t)(bn * 128 + row) * K + kt * 32 + col;
            __builtin_amdgcn_global_load_lds((const __attribute__((address_space(1))) void*)gb,
                (__attribute__((address_space(3))) void*)&Bs[buf][c * 512], 16, 0, 0);
        }
    };

    const int nt = K >> 5;
    stage(0, 0);
    __syncthreads();
    int cur = 0;
    for (int kt = 0; kt < nt; ++kt) {
        if (kt + 1 < nt) stage(cur ^ 1, kt + 1);
        const int ko = lgp * 8;
        short8 af[4], bfr[4];
#pragma unroll
        for (int m2 = 0; m2 < 4; ++m2)
            af[m2] = *(const short8*)&As[cur][(wr * 64 + m2 * 16 + lr) * 32 + ko];
#pragma unroll
        for (int n2 = 0; n2 < 4; ++n2)
            bfr[n2] = *(const short8*)&Bs[cur][(wc * 64 + n2 * 16 + lr) * 32 + ko];
#pragma unroll
        for (int m2 = 0; m2 < 4; ++m2)
#pragma unroll
            for (int n2 = 0; n2 < 4; ++n2)
                acc[m2][n2] = __builtin_amdgcn_mfma_f32_16x16x32_bf16(af[m2], bfr[n2], acc[m2][n2], 0, 0, 0);
        __syncthreads();
        cur ^= 1;
    }

#pragma unroll
    for (int n2 = 0; n2 < 4; ++n2) {
        int gn = bn * 128 + wc * 64 + n2 * 16 + lr;
        float sc = scale[gn] * 64.0f;
#pragma unroll
        for (int m2 = 0; m2 < 4; ++m2) {
            int gm0 = bm * 128 + wr * 64 + m2 * 16 + lgp * 4;
#pragma unroll
            for (int i = 0; i < 4; ++i)
                C[(size_t)(gm0 + i) * N + gn] = acc[m2][n2][i] * sc;
        }
    }
}

// ---------------- RoPE + relayout to head-major bf16 Q/K/V ----------------
// Q is pre-scaled by log2(e)/sqrt(HDIM): attention runs softmax in exp2 domain.
__global__ __launch_bounds__(256)
void rope_kernel(const float* __restrict__ qkv, const int* __restrict__ pos,
                 unsigned short* __restrict__ Qb, unsigned short* __restrict__ Kb,
                 unsigned short* __restrict__ Vb) {
    __shared__ float invf_t[64];
    if (threadIdx.x < 64)
        invf_t[threadIdx.x] = exp2f((float)threadIdx.x * -0.29580576f); // theta^(-j/64)
    __syncthreads();
    const int s = blockIdx.x;
    const float p = (float)pos[s];
    const float* row = qkv + (size_t)s * NQKV;
    const float qs = 0.12751793f;   // (1/sqrt(128)) * log2(e)
    for (int idx = threadIdx.x; idx < NQKV; idx += 256) {
        float v = row[idx];
        if (idx < HID + NKVH * HDIM) {      // q or k -> RoPE
            int base = (idx < HID) ? 0 : HID;
            int rel = idx - base;
            int h = rel >> 7, d = rel & 127;
            float ang = p * invf_t[d & 63];
            float sn, cs;
            sincosf(ang, &sn, &cs);
            float other = (d < 64) ? -row[base + h * 128 + d + 64]
                                   :  row[base + h * 128 + d - 64];
            float r = v * cs + other * sn;
            if (idx < HID) Qb[((size_t)h * S_LEN + s) * HDIM + d] = f2bf(r * qs);
            else           Kb[((size_t)h * S_LEN + s) * HDIM + d] = f2bf(r);
        } else {                             // v passthrough
            int rel = idx - (HID + NKVH * HDIM);
            int h = rel >> 7, d = rel & 127;
            Vb[((size_t)h * S_LEN + s) * HDIM + d] = f2bf(v);
        }
    }
}

// ---------------- causal GQA flash attention, 2-way split-KV ----------------
// grid (16, 2, 32): x = q-tile pair (handles qt=x and 31-x), y = kv half, z = head.
// 1024 blocks -> 3/CU at 48KB LDS. Writes UNNORMALIZED bf16 partial O~ + (m,l)
// per q-row; fwht_merge combines. Swapped QK^T, exp2-domain in-reg softmax,
// permuted Vt (single-b128 PV fragments), defer-max. Barrier structure: b1 =
// __syncthreads (drains prev stage+V loads); stage/scatter/V-prefetch before
// QK^T; b2 = lgkmcnt(0)+s_barrier only (staging flies through PV).
__global__ __launch_bounds__(256)
void attn_kernel(const unsigned short* __restrict__ Q, const unsigned short* __restrict__ K,
                 const unsigned short* __restrict__ V, unsigned short* __restrict__ Opart,
                 float* __restrict__ ML) {
    const int hf = blockIdx.y;
    const int hd = blockIdx.z;
    const int kvh = hd >> 2;
    const int tid = threadIdx.x, wv = tid >> 6, lane = tid & 63;
    const int lr = lane & 15, lgp = lane >> 4;

    __shared__ __attribute__((aligned(16))) unsigned short Ks[2][64 * 128];
    __shared__ __attribute__((aligned(16))) unsigned short Vt[128 * 64];

    int koff[4];
#pragma unroll
    for (int j = 0; j < 4; ++j) {
        int a = (wv * 4 + j) * 512 + lane * 8;
        koff[j] = a ^ (((a >> 7) & 7) << 3);
    }
    const int vpos = ((lane >> 2) & 3) * 16 + (lane >> 4) * 4 + (lane & 3);
    const unsigned short* Kg = K + (size_t)kvh * S_LEN * HDIM;
    const unsigned short* Vg = V + (size_t)kvh * S_LEN * HDIM;

    auto stageK = [&](int buf, int kb) {
        const unsigned short* kg = Kg + (size_t)kb * 64 * HDIM;
#pragma unroll
        for (int j = 0; j < 4; ++j) {
            __builtin_amdgcn_global_load_lds(
                (const __attribute__((address_space(1))) void*)(kg + koff[j]),
                (__attribute__((address_space(3))) void*)&Ks[buf][(wv * 4 + j) * 512], 16, 0, 0);
        }
    };

#pragma unroll 1
    for (int rep = 0; rep < 2; ++rep) {
        const int qt = rep ? (31 - (int)blockIdx.x) : (int)blockIdx.x;
        const int qg = qt * 64 + wv * 16 + lr;   // this lane's q row
        const int n = qt + 1, mid = (n + 1) >> 1;
        const int s = hf ? mid : 0, e = hf ? n : mid;

        __syncthreads();   // LDS reuse guard across reps

        short8 aq[4];
        {
            const unsigned short* qp = Q + ((size_t)hd * S_LEN + qg) * HDIM + lgp * 8;
#pragma unroll
            for (int kk = 0; kk < 4; ++kk) aq[kk] = *(const short8*)(qp + kk * 32);
        }

        f32x4 oacc[8] = {};
        float m_i = -3.0e38f, l_i = 0.f;

        short8 vcur[4];
        if (s < e) {
            stageK(s & 1, s);
            const unsigned short* vp = Vg + (size_t)s * 64 * HDIM + lane * HDIM + wv * 32;
#pragma unroll
            for (int r2 = 0; r2 < 4; ++r2) vcur[r2] = *(const short8*)(vp + r2 * 8);
        }

#pragma unroll 1
        for (int kb = s; kb < e; ++kb) {
            const int cur = kb & 1;
            __syncthreads();   // b1: drains prev-iter stage + V loads; prev PV done

            if (kb + 1 < e) stageK(cur ^ 1, kb + 1);
            // scatter V regs -> permuted+swizzled Vt (QK^T doesn't touch Vt)
#pragma unroll
            for (int r2 = 0; r2 < 4; ++r2) {
#pragma unroll
                for (int en = 0; en < 8; ++en) {
                    int d = wv * 32 + r2 * 8 + en;
                    Vt[(d * 64 + vpos) ^ ((d & 7) << 3)] = ((const unsigned short*)&vcur[r2])[en];
                }
            }
            if (kb + 1 < e) {
                const unsigned short* vp = Vg + (size_t)(kb + 1) * 64 * HDIM + lane * HDIM + wv * 32;
#pragma unroll
                for (int r2 = 0; r2 < 4; ++r2) vcur[r2] = *(const short8*)(vp + r2 * 8);
            }

            __builtin_amdgcn_s_setprio(1);
            // QK^T swapped: sc[nt2] rows = kv (nt2*16 + 4*lgp + i), cols = q (lr)
            f32x4 sc[4];
#pragma unroll
            for (int nt2 = 0; nt2 < 4; ++nt2) {
                f32x4 a = {};
                const int krow = nt2 * 16 + lr;
                const int swz = (krow & 7) << 3;
#pragma unroll
                for (int kk = 0; kk < 4; ++kk) {
                    short8 ak = *(const short8*)&Ks[cur][(krow * 128 + kk * 32 + lgp * 8) ^ swz];
                    a = __builtin_amdgcn_mfma_f32_16x16x32_bf16(ak, aq[kk], a, 0, 0, 0);
                }
                sc[nt2] = a;
            }
            __builtin_amdgcn_s_setprio(0);

            if (kb == qt) {    // causal mask (diag tile)
#pragma unroll
                for (int nt2 = 0; nt2 < 4; ++nt2)
#pragma unroll
                    for (int i = 0; i < 4; ++i) {
                        int kvg = kb * 64 + nt2 * 16 + 4 * lgp + i;
                        if (kvg > qg) sc[nt2][i] = -1.0e30f;
                    }
            }

            // in-register online softmax (exp2 domain) for q = lr
            float vmax = fmaxf(fmaxf(fmaxf(sc[0][0], sc[0][1]), fmaxf(sc[0][2], sc[0][3])),
                               fmaxf(fmaxf(sc[1][0], sc[1][1]), fmaxf(sc[1][2], sc[1][3])));
            vmax = fmaxf(vmax, fmaxf(fmaxf(fmaxf(sc[2][0], sc[2][1]), fmaxf(sc[2][2], sc[2][3])),
                                     fmaxf(fmaxf(sc[3][0], sc[3][1]), fmaxf(sc[3][2], sc[3][3]))));
            vmax = fmaxf(vmax, __shfl_xor(vmax, 16));
            vmax = fmaxf(vmax, __shfl_xor(vmax, 32));

            if (!__all(vmax <= m_i + 11.0f)) {   // defer-max: P bounded by 2^11
                float mn = fmaxf(m_i, vmax);
                float fe = __builtin_amdgcn_exp2f(m_i - mn);
                m_i = mn;
                l_i *= fe;
                float feb[4];
#pragma unroll
                for (int i2 = 0; i2 < 4; ++i2) feb[i2] = __shfl(fe, 4 * lgp + i2);
#pragma unroll
                for (int t = 0; t < 8; ++t)
#pragma unroll
                    for (int i2 = 0; i2 < 4; ++i2) oacc[t][i2] *= feb[i2];
            }

            float rs = 0.f;
#pragma unroll
            for (int nt2 = 0; nt2 < 4; ++nt2)
#pragma unroll
                for (int i = 0; i < 4; ++i) {
                    float pv = __builtin_amdgcn_exp2f(sc[nt2][i] - m_i);
                    sc[nt2][i] = pv;
                    rs += pv;
                }
            rs += __shfl_xor(rs, 16);
            rs += __shfl_xor(rs, 32);
            l_i += rs;

            // P pack (A-operand, permuted-k convention)
            union { unsigned u[4]; short8 sv; } a0, a1;
            a0.u[0] = cvt_pk_bf16(sc[0][0], sc[0][1]);
            a0.u[1] = cvt_pk_bf16(sc[0][2], sc[0][3]);
            a0.u[2] = cvt_pk_bf16(sc[1][0], sc[1][1]);
            a0.u[3] = cvt_pk_bf16(sc[1][2], sc[1][3]);
            a1.u[0] = cvt_pk_bf16(sc[2][0], sc[2][1]);
            a1.u[1] = cvt_pk_bf16(sc[2][2], sc[2][3]);
            a1.u[2] = cvt_pk_bf16(sc[3][0], sc[3][1]);
            a1.u[3] = cvt_pk_bf16(sc[3][2], sc[3][3]);

            // b2: scatter visibility only — NO vmcnt drain (staging keeps flying)
            asm volatile("s_waitcnt lgkmcnt(0)" ::: "memory");
            __builtin_amdgcn_sched_barrier(0);
            __builtin_amdgcn_s_barrier();

            // PV: B fragments are contiguous b128 reads from permuted Vt
            __builtin_amdgcn_s_setprio(1);
#pragma unroll
            for (int t = 0; t < 8; ++t) {
                const int d = t * 16 + lr;
                const int swz = (d & 7) << 3;
                const int dbase = d * 64 + lgp * 16;
                short8 bv0 = *(const short8*)&Vt[(dbase) ^ swz];
                short8 bv1 = *(const short8*)&Vt[(dbase + 8) ^ swz];
                oacc[t] = __builtin_amdgcn_mfma_f32_16x16x32_bf16(a0.sv, bv0, oacc[t], 0, 0, 0);
                oacc[t] = __builtin_amdgcn_mfma_f32_16x16x32_bf16(a1.sv, bv1, oacc[t], 0, 0, 0);
            }
            __builtin_amdgcn_s_setprio(0);
        }

        // epilogue: unnormalized bf16 partial O~ + (m,l)
        unsigned short* op = Opart + ((size_t)hf * S_LEN + qt * 64 + wv * 16 + 4 * lgp) * HID
                           + hd * HDIM + lr;
#pragma unroll
        for (int t = 0; t < 8; ++t)
#pragma unroll
            for (int i2 = 0; i2 < 4; ++i2)
                op[(size_t)i2 * HID + t * 16] = f2bf(oacc[t][i2]);
        if (lgp == 0) {
            float2* mlp = (float2*)ML;
            mlp[((size_t)hf * S_LEN + qt * 64 + wv * 16 + lr) * NHEAD + hd] =
                make_float2(m_i, l_i);
        }
    }
}

// ---------------- launch ----------------
extern "C" void kernel_launch(void* const* d_in, const int* in_sizes, int n_in,
                              void* d_out, int out_size, void* d_ws, size_t ws_size,
                              hipStream_t stream) {
    const float* hidden = (const float*)d_in[0];
    const int*   pos    = (const int*)d_in[1];
    const float* su_qkv = (const float*)d_in[2];
    const float* su_o   = (const float*)d_in[3];
    const float* ws_qkv = (const float*)d_in[4];
    const float* ws_o   = (const float*)d_in[5];
    const float* Wq     = (const float*)d_in[6];
    const float* Wk     = (const float*)d_in[7];
    const float* Wv     = (const float*)d_in[8];
    const float* Wo     = (const float*)d_in[9];
    float* out = (float*)d_out;

    char* ws = (char*)d_ws;
    unsigned short* Wcat = (unsigned short*)(ws);                        // [6144][4096] bf16
    unsigned short* Wob  = (unsigned short*)(ws + 50331648);             // [4096][4096] bf16
    unsigned short* xb   = (unsigned short*)(ws + 83886080);             // [2048][4096] bf16
    float*          qkv  = (float*)(ws + 100663296);                     // [2048][6144] f32
    unsigned short* Opart= (unsigned short*)(ws + 100663296);            // [2][2048][4096] bf16 (reuses qkv)
    float*          ML   = (float*)(ws + 100663296 + 33554432);          // [2][2048][32][2] f32
    unsigned short* Qb   = (unsigned short*)(ws + 150994944);            // [32][2048][128] bf16
    unsigned short* Kb   = Qb + (size_t)NHEAD * S_LEN * HDIM;
    unsigned short* Vb   = Kb + (size_t)NKVH * S_LEN * HDIM;

    cvt4_kernel<<<2560, 256, 0, stream>>>(Wq, Wk, Wv, Wo, Wcat, Wob);

    fwht_kernel<<<S_LEN, 256, 0, stream>>>(hidden, su_qkv, xb);
    gemm_bt<<<dim3(NQKV / 128, S_LEN / 128), 256, 0, stream>>>(xb, Wcat, ws_qkv, qkv, S_LEN, NQKV, HID);
    rope_kernel<<<S_LEN, 256, 0, stream>>>(qkv, pos, Qb, Kb, Vb);
    attn_kernel<<<dim3(16, 2, NHEAD), 256, 0, stream>>>(Qb, Kb, Vb, Opart, ML);
    fwht_merge<<<S_LEN, 256, 0, stream>>>(Opart, ML, su_o, xb);
    gemm_bt<<<dim3(HID / 128, S_LEN / 128), 256, 0, stream>>>(xb, Wob, ws_o, out, S_LEN, HID, HID);
}